// Round 8
// baseline (139.672 us; speedup 1.0000x reference)
//
#include <hip/hip_runtime.h>

// MetaUpSampler via bf16 MFMA — round 8.
// R7 lessons: (a) ~60us of dur_us is harness poison/restore (untouchable);
// (b) meta is latency/occupancy-starved (all pipes <14%, occ 30%).
// R8: 2 output rows per block (6 waves / 384 thr) sharing staged input rows:
//   4 rows staged instead of 6 (-33% fetch), LDS 33.8KB -> 4 blocks/CU
//   = 24 waves/CU latency hiding. Per-thread state unchanged vs R5 (no spill).

#define HH   192
#define WWD  192
#define SS   4
#define OC   3
#define PO   48
#define HID  256
#define W2LD 1728

typedef short  bf16x8 __attribute__((ext_vector_type(8)));
typedef float  f32x4  __attribute__((ext_vector_type(4)));

static __device__ __forceinline__ short f2bf(float f) {
    unsigned u = __float_as_uint(f);
    unsigned r = (u + 0x7fffu + ((u >> 16) & 1u)) >> 16;   // RNE
    return (short)r;
}

// ---------------- Stage A: MLP -> dynamic weights, bf16, [tap][po][c] -------
// Grid: dim3(7,4) x 256 threads. Thread = one W2 column x 4 p-values.
__global__ __launch_bounds__(256) void lw_kernel(
        const float* __restrict__ W1, const float* __restrict__ b1,
        const float* __restrict__ W2, const float* __restrict__ b2,
        short* __restrict__ lwb) {
    __shared__ float hlds[HID * 16];   // [h][p] transposed, 16 KB
    const int tid = threadIdx.x;       // == hidden index h for the MLP part
    {
        const float w0 = W1[tid], w1 = W1[HID + tid], w2 = W1[2 * HID + tid], bb = b1[tid];
#pragma unroll
        for (int g = 0; g < 4; ++g) {
            float4 hv;
            float* hp = (float*)&hv;
#pragma unroll
            for (int pp = 0; pp < 4; ++pp) {
                const int p = g * 4 + pp;
                const float pi = (float)(p >> 2) * 0.25f;
                const float pj = (float)(p & 3) * 0.25f;
                const float v = 0.25f * w0 + pi * w1 + pj * w2 + bb;
                hp[pp] = v > 0.f ? v : 0.f;
            }
            *(float4*)&hlds[tid * 16 + g * 4] = hv;
        }
    }
    __syncthreads();

    const int col = blockIdx.x * 256 + tid;   // 0..1791 (guard at 1728)
    const int pg  = blockIdx.y;               // p-group (wave-uniform)
    if (col < W2LD) {
        float a0 = 0.f, a1 = 0.f, a2 = 0.f, a3 = 0.f;
#pragma unroll 32
        for (int h = 0; h < HID; ++h) {
            const float v  = W2[h * W2LD + col];                      // coalesced 4B
            const float4 hv = *(const float4*)&hlds[h * 16 + pg * 4]; // uniform b128
            a0 += hv.x * v; a1 += hv.y * v; a2 += hv.z * v; a3 += hv.w * v;
        }
        const float bv = b2[col];
        const int o = col % 3, kc = col / 3;
        const int tap = kc % 9, c = kc / 9;
        const int p0 = pg * 4;
        lwb[(tap * PO + (p0 + 0) * 3 + o) * 64 + c] = f2bf(a0 + bv);
        lwb[(tap * PO + (p0 + 1) * 3 + o) * 64 + c] = f2bf(a1 + bv);
        lwb[(tap * PO + (p0 + 2) * 3 + o) * 64 + c] = f2bf(a2 + bv);
        lwb[(tap * PO + (p0 + 3) * 3 + o) * 64 + c] = f2bf(a3 + bv);
    }
}

// ---------------- Stage B: MFMA dynamic conv --------------------------------
// Block: 64-wide strip x 2 output rows x 48 po. 6 waves (384 thr):
//   wave role (compute): pt = wv%3 po-tile, rr = wv/3 output row.
//   wave role (staging): waves 0..3 stage input row h0-1+wv.
__global__ __launch_bounds__(384, 4) void meta_up_mfma(
        const float* __restrict__ x, const short* __restrict__ lwb,
        float* __restrict__ out) {
    __shared__ __align__(16) short smem[4 * 66 * 64];   // 33,792 B
    short* xlds = smem;                    // [r 0..3][j 0..65][c], XOR'd 16B blocks
    float* obuf = (float*)smem;            // reused post-MFMA: 2 x 12 x 260 floats

    // XCD-band swizzle: 1152 tiles = 8 XCDs x 144; contiguous (n,hb) per XCD.
    const int tile = (blockIdx.x & 7) * 144 + (blockIdx.x >> 3);
    const int n   = tile / (96 * 3);
    const int rem = tile % (96 * 3);
    const int hb  = rem / 3;               // row pair: h0, h0+1
    const int wch = rem % 3;
    const int h0  = hb * 2;
    const int w0  = wch * 64;

    const int tid  = threadIdx.x;
    const int lane = tid & 63, wv = tid >> 6;     // wv 0..5
    const int quad = lane >> 4, l15 = lane & 15;
    const int pt = wv % 3;                 // po-tile
    const int rr = wv / 3;                 // output row within pair

    // B fragments: po-tile pt (16 po), all 9 taps x 2 K-chunks.
    bf16x8 Bfrag[18];
#pragma unroll
    for (int tap = 0; tap < 9; ++tap)
#pragma unroll
        for (int kc2 = 0; kc2 < 2; ++kc2)
            Bfrag[tap * 2 + kc2] = *(const bf16x8*)
                &lwb[(tap * PO + pt * 16 + l15) * 64 + kc2 * 32 + quad * 8];

    // Stage 4 input rows (gr = h0-1 .. h0+2), waves 0..3 one row each.
    // Lane = column j (coalesced); gather 8 channels -> one ds_write_b128.
    if (wv < 4) {
        const int r  = wv;
        const int gr = h0 - 1 + r;
        const bool rok = (unsigned)gr < (unsigned)HH;
        const int gc  = w0 - 1 + lane;
        const bool cok = rok && ((unsigned)gc < (unsigned)WWD);
        const float* __restrict__ xr =
            x + ((size_t)n * 64 * HH + (size_t)(rok ? gr : 0)) * WWD + (cok ? gc : 0);
#pragma unroll
        for (int cb = 0; cb < 8; ++cb) {
            bf16x8 pk;
#pragma unroll
            for (int cc = 0; cc < 8; ++cc) {
                const float vv = cok ? xr[(size_t)(cb * 8 + cc) * HH * WWD] : 0.f;
                pk[cc] = f2bf(vv);
            }
            *(bf16x8*)&xlds[(r * 66 + lane) * 64 + ((cb ^ (lane & 7)) << 3)] = pk;
        }
        if (lane < 16) {                 // tail columns j = 64, 65
            const int jt = 64 + (lane >> 3);
            const int cb = lane & 7;
            const int gc2 = w0 - 1 + jt;
            const bool cok2 = rok && ((unsigned)gc2 < (unsigned)WWD);
            bf16x8 pk;
#pragma unroll
            for (int cc = 0; cc < 8; ++cc) {
                const float vv = cok2 ?
                    x[((size_t)(n * 64 + cb * 8 + cc) * HH + gr) * WWD + gc2] : 0.f;
                pk[cc] = f2bf(vv);
            }
            *(bf16x8*)&xlds[(r * 66 + jt) * 64 + ((cb ^ (jt & 7)) << 3)] = pk;
        }
    }
    __syncthreads();

    // Main loop: FULLY unrolled 9 taps x 2 K-chunks x 4 m-tiles = 72 MFMAs.
    f32x4 acc[4];
#pragma unroll
    for (int mt = 0; mt < 4; ++mt) acc[mt] = (f32x4){0.f, 0.f, 0.f, 0.f};

#pragma unroll
    for (int tap = 0; tap < 9; ++tap) {
        const int di = tap / 3, dj = tap % 3;
#pragma unroll
        for (int kc2 = 0; kc2 < 2; ++kc2) {
            const bf16x8 b = Bfrag[tap * 2 + kc2];
#pragma unroll
            for (int mt = 0; mt < 4; ++mt) {
                const int col = mt * 16 + l15 + dj;           // 0..65
                const int blk = (kc2 * 4 + quad) ^ (col & 7);
                bf16x8 a = *(const bf16x8*)
                    &xlds[((rr + di) * 66 + col) * 64 + (blk << 3)];
                acc[mt] = __builtin_amdgcn_mfma_f32_16x16x32_bf16(a, b, acc[mt], 0, 0, 0);
            }
        }
    }

    // Epilogue: transpose D through LDS -> full-line coalesced stores.
    __syncthreads();                       // all xlds reads complete
    {
        const int po = pt * 16 + l15;
        const int o  = po % 3;
        const int p  = po / 3;
        const int si = p >> 2, sj = p & 3;
        const int osi = o * 4 + si;
#pragma unroll
        for (int mt = 0; mt < 4; ++mt)
#pragma unroll
            for (int r4 = 0; r4 < 4; ++r4) {
                const int wl = mt * 16 + quad * 4 + r4;
                obuf[rr * 3120 + osi * 260 + wl * 4 + sj] = acc[mt][r4];
            }
    }
    __syncthreads();
    {
        const int osi2 = tid >> 4;         // 0..23
        const int c16  = tid & 15;
        const int rw   = osi2 / 12;        // output row within pair
        const int osi  = osi2 % 12;
        const int o = osi >> 2, si = osi & 3;
        const size_t base =
            ((size_t)(n * OC + o) * (SS * HH) + (size_t)(SS * (h0 + rw) + si)) * (SS * WWD)
            + (size_t)(4 * w0) + c16 * 16;
        const float* __restrict__ src = &obuf[rw * 3120 + osi * 260 + c16 * 16];
#pragma unroll
        for (int i = 0; i < 4; ++i)        // 64B contiguous per thread
            *(float4*)&out[base + i * 4] = *(const float4*)&src[i * 4];
    }
}

extern "C" void kernel_launch(void* const* d_in, const int* in_sizes, int n_in,
                              void* d_out, int out_size, void* d_ws, size_t ws_size,
                              hipStream_t stream) {
    const float* x  = (const float*)d_in[0];
    const float* W1 = (const float*)d_in[1];
    const float* b1 = (const float*)d_in[2];
    const float* W2 = (const float*)d_in[3];
    const float* b2 = (const float*)d_in[4];
    float* out = (float*)d_out;
    short* lwb = (short*)d_ws;   // 27648 bf16 = 55 KB

    lw_kernel<<<dim3(7, 4), 256, 0, stream>>>(W1, b1, W2, b2, lwb);
    meta_up_mfma<<<4 * 96 * 3, 384, 0, stream>>>(x, lwb, out);
}